// Round 2
// baseline (1141.292 us; speedup 1.0000x reference)
//
#include <hip/hip_runtime.h>

typedef unsigned short u16;
typedef __attribute__((ext_vector_type(8))) short bf16x8;
typedef __attribute__((ext_vector_type(8))) unsigned short u16x8;
typedef __attribute__((ext_vector_type(4))) float f32x4;

#define NTOK 8192
#define DDIM 1024
#define HDIM 4096
#define NEXP 8
#define BKP 40   // padded B^T leading dim (bf16 elems)

__device__ __forceinline__ u16 f2b(float f) {
  unsigned u = __float_as_uint(f);
  u += 0x7fffu + ((u >> 16) & 1u);   // RNE
  return (u16)(u >> 16);
}

// ---------------- gating: softmax over 8 experts, top-2, bucket by expert ----
__global__ void gate_kernel(const float* __restrict__ x, const float* __restrict__ Wg,
                            const float* __restrict__ bg, int* __restrict__ counts,
                            int* __restrict__ pair_tok, float* __restrict__ pair_w)
{
  int lane = threadIdx.x & 63;
  int wave = threadIdx.x >> 6;
  int tok = blockIdx.x * 4 + wave;
  const float* xr = x + (size_t)tok * DDIM + lane * 16;
  float acc[NEXP];
#pragma unroll
  for (int e = 0; e < NEXP; ++e) acc[e] = 0.f;
#pragma unroll
  for (int j = 0; j < 16; ++j) {
    float xf = xr[j];
    const float* wr = Wg + (size_t)(lane * 16 + j) * NEXP;
    float4 wa = *(const float4*)(wr);
    float4 wb = *(const float4*)(wr + 4);
    acc[0] = fmaf(xf, wa.x, acc[0]);
    acc[1] = fmaf(xf, wa.y, acc[1]);
    acc[2] = fmaf(xf, wa.z, acc[2]);
    acc[3] = fmaf(xf, wa.w, acc[3]);
    acc[4] = fmaf(xf, wb.x, acc[4]);
    acc[5] = fmaf(xf, wb.y, acc[5]);
    acc[6] = fmaf(xf, wb.z, acc[6]);
    acc[7] = fmaf(xf, wb.w, acc[7]);
  }
#pragma unroll
  for (int off = 32; off > 0; off >>= 1) {
#pragma unroll
    for (int e = 0; e < NEXP; ++e) acc[e] += __shfl_xor(acc[e], off, 64);
  }
  if (lane == 0) {
    float l[NEXP];
    float mx = -3.4e38f;
#pragma unroll
    for (int e = 0; e < NEXP; ++e) { l[e] = acc[e] + bg[e]; mx = fmaxf(mx, l[e]); }
    float s = 0.f;
#pragma unroll
    for (int e = 0; e < NEXP; ++e) { l[e] = __expf(l[e] - mx); s += l[e]; }
    float inv = 1.f / s;
    float v1 = -1.f; int i1 = 0;
#pragma unroll
    for (int e = 0; e < NEXP; ++e) { if (l[e] > v1) { v1 = l[e]; i1 = e; } }
    float v2 = -1.f; int i2 = 0;
#pragma unroll
    for (int e = 0; e < NEXP; ++e) { if (e != i1 && l[e] > v2) { v2 = l[e]; i2 = e; } }
    int p1 = atomicAdd(&counts[i1], 1);
    pair_tok[i1 * NTOK + p1] = tok;
    pair_w[i1 * NTOK + p1] = v1 * inv;   // raw top-k softmax prob (not renormalized)
    int p2 = atomicAdd(&counts[i2], 1);
    pair_tok[i2 * NTOK + p2] = tok;
    pair_w[i2 * NTOK + p2] = v2 * inv;
  }
}

__global__ void offsets_kernel(const int* __restrict__ counts, int* __restrict__ offsets) {
  if (threadIdx.x == 0) {
    int s = 0;
    for (int e = 0; e < NEXP; ++e) { offsets[e] = s; s += counts[e]; }
  }
}

// ---------------- grouped GEMM1: h = relu(gather(x) @ W1[e] + b1[e]) --------
__global__ __launch_bounds__(256) void gemm1_kernel(
    const float* __restrict__ x, const float* __restrict__ W1,
    const float* __restrict__ b1, const int* __restrict__ counts,
    const int* __restrict__ offsets, const int* __restrict__ pair_tok,
    u16* __restrict__ h, int hp, int p0)
{
  int e = blockIdx.z;
  int cnt = counts[e];
  int i0 = blockIdx.y * 128;
  if (i0 >= cnt) return;
  int n0 = blockIdx.x * 128;               // column offset within this phase

  __shared__ __align__(16) u16 As[128 * 32];
  __shared__ __align__(16) u16 Bs[128 * BKP];

  int t = threadIdx.x;
  int lane = t & 63;
  int wave = t >> 6;
  int rlim = cnt - i0;

  const int* tokp = pair_tok + e * NTOK + i0;
  int arow = t >> 2;
  int c8 = (t & 3) * 8;
  const float* xa0 = x + (size_t)tokp[min(arow, rlim - 1)] * DDIM + c8;
  const float* xa1 = x + (size_t)tokp[min(arow + 64, rlim - 1)] * DDIM + c8;
  u16* adst0 = As + arow * 32 + c8;
  u16* adst1 = As + (arow + 64) * 32 + c8;

  int nl = (t & 31) * 4;
  int kl = (t >> 5) * 4;
  const float* Bsrc = W1 + (size_t)e * DDIM * HDIM + (p0 + n0) + nl;

  f32x4 acc[4][4] = {};
  int wrr = (wave >> 1) * 64;
  int wc = (wave & 1) * 64;
  int ln = lane & 15;
  int q = lane >> 4;

  for (int k0 = 0; k0 < DDIM; k0 += 32) {
    float4 a00 = *(const float4*)(xa0 + k0);
    float4 a01 = *(const float4*)(xa0 + k0 + 4);
    float4 a10 = *(const float4*)(xa1 + k0);
    float4 a11 = *(const float4*)(xa1 + k0 + 4);
    const float* bp = Bsrc + (size_t)(k0 + kl) * HDIM;
    float4 v0 = *(const float4*)(bp);
    float4 v1 = *(const float4*)(bp + HDIM);
    float4 v2 = *(const float4*)(bp + 2 * HDIM);
    float4 v3 = *(const float4*)(bp + 3 * HDIM);
    __syncthreads();   // previous iteration's LDS reads complete
    u16x8 pa0, pa1;
    pa0[0] = f2b(a00.x); pa0[1] = f2b(a00.y); pa0[2] = f2b(a00.z); pa0[3] = f2b(a00.w);
    pa0[4] = f2b(a01.x); pa0[5] = f2b(a01.y); pa0[6] = f2b(a01.z); pa0[7] = f2b(a01.w);
    pa1[0] = f2b(a10.x); pa1[1] = f2b(a10.y); pa1[2] = f2b(a10.z); pa1[3] = f2b(a10.w);
    pa1[4] = f2b(a11.x); pa1[5] = f2b(a11.y); pa1[6] = f2b(a11.z); pa1[7] = f2b(a11.w);
    *(u16x8*)adst0 = pa0;
    *(u16x8*)adst1 = pa1;
    ushort4 w0, w1, w2, w3;
    w0.x = f2b(v0.x); w0.y = f2b(v1.x); w0.z = f2b(v2.x); w0.w = f2b(v3.x);
    w1.x = f2b(v0.y); w1.y = f2b(v1.y); w1.z = f2b(v2.y); w1.w = f2b(v3.y);
    w2.x = f2b(v0.z); w2.y = f2b(v1.z); w2.z = f2b(v2.z); w2.w = f2b(v3.z);
    w3.x = f2b(v0.w); w3.y = f2b(v1.w); w3.z = f2b(v2.w); w3.w = f2b(v3.w);
    *(ushort4*)(Bs + (nl + 0) * BKP + kl) = w0;
    *(ushort4*)(Bs + (nl + 1) * BKP + kl) = w1;
    *(ushort4*)(Bs + (nl + 2) * BKP + kl) = w2;
    *(ushort4*)(Bs + (nl + 3) * BKP + kl) = w3;
    __syncthreads();
    bf16x8 af[4], bfr[4];
#pragma unroll
    for (int mt = 0; mt < 4; ++mt)
      af[mt] = *(const bf16x8*)(As + (wrr + mt * 16 + ln) * 32 + q * 8);
#pragma unroll
    for (int nt = 0; nt < 4; ++nt)
      bfr[nt] = *(const bf16x8*)(Bs + (wc + nt * 16 + ln) * BKP + q * 8);
#pragma unroll
    for (int mt = 0; mt < 4; ++mt)
#pragma unroll
      for (int nt = 0; nt < 4; ++nt)
        acc[mt][nt] = __builtin_amdgcn_mfma_f32_16x16x32_bf16(af[mt], bfr[nt], acc[mt][nt], 0, 0, 0);
  }

  int ob = offsets[e];
  float bb[4];
#pragma unroll
  for (int nt = 0; nt < 4; ++nt)
    bb[nt] = b1[(size_t)e * HDIM + p0 + n0 + wc + nt * 16 + ln];
  size_t hbase = (size_t)(ob + i0) * hp + n0 + wc;
#pragma unroll
  for (int mt = 0; mt < 4; ++mt) {
#pragma unroll
    for (int r = 0; r < 4; ++r) {
      int row = wrr + mt * 16 + q * 4 + r;
      if (row < rlim) {
        u16* hrow = h + hbase + (size_t)row * hp;
#pragma unroll
        for (int nt = 0; nt < 4; ++nt) {
          float v = acc[mt][nt][r] + bb[nt];
          hrow[nt * 16 + ln] = f2b(fmaxf(v, 0.f));
        }
      }
    }
  }
}

// ---------------- grouped GEMM2: out += w * (h @ W2[e] + b2[e]) --------------
__global__ __launch_bounds__(256) void gemm2_kernel(
    const u16* __restrict__ h, const float* __restrict__ W2,
    const float* __restrict__ b2v, const int* __restrict__ counts,
    const int* __restrict__ offsets, const int* __restrict__ pair_tok,
    const float* __restrict__ pair_w, float* __restrict__ out,
    int hp, int p0, int addb2)
{
  int e = blockIdx.z;
  int cnt = counts[e];
  int i0 = blockIdx.y * 128;
  if (i0 >= cnt) return;
  int n0 = blockIdx.x * 128;

  __shared__ __align__(16) u16 As[128 * 32];
  __shared__ __align__(16) u16 Bs[128 * BKP];

  int t = threadIdx.x;
  int lane = t & 63;
  int wave = t >> 6;
  int rlim = cnt - i0;
  int rbase = offsets[e] + i0;

  int arow = t >> 2;
  int c8 = (t & 3) * 8;
  const u16* ha0 = h + (size_t)(rbase + arow) * hp + c8;
  const u16* ha1 = h + (size_t)(rbase + arow + 64) * hp + c8;
  u16* adst0 = As + arow * 32 + c8;
  u16* adst1 = As + (arow + 64) * 32 + c8;

  int nl = (t & 31) * 4;
  int kl = (t >> 5) * 4;
  const float* Bsrc = W2 + (size_t)e * HDIM * DDIM + (size_t)p0 * DDIM + n0 + nl;

  f32x4 acc[4][4] = {};
  int wrr = (wave >> 1) * 64;
  int wc = (wave & 1) * 64;
  int ln = lane & 15;
  int q = lane >> 4;

  for (int k0 = 0; k0 < hp; k0 += 32) {
    u16x8 hv0 = *(const u16x8*)(ha0 + k0);
    u16x8 hv1 = *(const u16x8*)(ha1 + k0);
    const float* bp = Bsrc + (size_t)(k0 + kl) * DDIM;
    float4 v0 = *(const float4*)(bp);
    float4 v1 = *(const float4*)(bp + DDIM);
    float4 v2 = *(const float4*)(bp + 2 * DDIM);
    float4 v3 = *(const float4*)(bp + 3 * DDIM);
    __syncthreads();
    *(u16x8*)adst0 = hv0;
    *(u16x8*)adst1 = hv1;
    ushort4 w0, w1, w2, w3;
    w0.x = f2b(v0.x); w0.y = f2b(v1.x); w0.z = f2b(v2.x); w0.w = f2b(v3.x);
    w1.x = f2b(v0.y); w1.y = f2b(v1.y); w1.z = f2b(v2.y); w1.w = f2b(v3.y);
    w2.x = f2b(v0.z); w2.y = f2b(v1.z); w2.z = f2b(v2.z); w2.w = f2b(v3.z);
    w3.x = f2b(v0.w); w3.y = f2b(v1.w); w3.z = f2b(v2.w); w3.w = f2b(v3.w);
    *(ushort4*)(Bs + (nl + 0) * BKP + kl) = w0;
    *(ushort4*)(Bs + (nl + 1) * BKP + kl) = w1;
    *(ushort4*)(Bs + (nl + 2) * BKP + kl) = w2;
    *(ushort4*)(Bs + (nl + 3) * BKP + kl) = w3;
    __syncthreads();
    bf16x8 af[4], bfr[4];
#pragma unroll
    for (int mt = 0; mt < 4; ++mt)
      af[mt] = *(const bf16x8*)(As + (wrr + mt * 16 + ln) * 32 + q * 8);
#pragma unroll
    for (int nt = 0; nt < 4; ++nt)
      bfr[nt] = *(const bf16x8*)(Bs + (wc + nt * 16 + ln) * BKP + q * 8);
#pragma unroll
    for (int mt = 0; mt < 4; ++mt)
#pragma unroll
      for (int nt = 0; nt < 4; ++nt)
        acc[mt][nt] = __builtin_amdgcn_mfma_f32_16x16x32_bf16(af[mt], bfr[nt], acc[mt][nt], 0, 0, 0);
  }

  float bb[4];
#pragma unroll
  for (int nt = 0; nt < 4; ++nt)
    bb[nt] = addb2 ? b2v[(size_t)e * DDIM + n0 + wc + nt * 16 + ln] : 0.f;
#pragma unroll
  for (int mt = 0; mt < 4; ++mt) {
#pragma unroll
    for (int r = 0; r < 4; ++r) {
      int row = wrr + mt * 16 + q * 4 + r;
      if (row < rlim) {
        int i = i0 + row;
        int tk = pair_tok[e * NTOK + i];
        float w = pair_w[e * NTOK + i];
        float* orow = out + (size_t)tk * DDIM + n0 + wc;
#pragma unroll
        for (int nt = 0; nt < 4; ++nt)
          atomicAdd(orow + nt * 16 + ln, (acc[mt][nt][r] + bb[nt]) * w);
      }
    }
  }
}

// ---------------- host launch ------------------------------------------------
extern "C" void kernel_launch(void* const* d_in, const int* in_sizes, int n_in,
                              void* d_out, int out_size, void* d_ws, size_t ws_size,
                              hipStream_t stream)
{
  const float* x  = (const float*)d_in[0];
  const float* Wg = (const float*)d_in[1];
  const float* bg = (const float*)d_in[2];
  const float* W1 = (const float*)d_in[3];
  const float* b1 = (const float*)d_in[4];
  const float* W2 = (const float*)d_in[5];
  const float* b2 = (const float*)d_in[6];
  float* out = (float*)d_out;

  char* ws = (char*)d_ws;
  int*   counts   = (int*)(ws + 0);
  int*   offsets  = (int*)(ws + 64);
  int*   pair_tok = (int*)(ws + 4096);
  float* pair_w   = (float*)(ws + 4096 + 262144);
  u16*   hbuf     = (u16*)(ws + 528384);
  size_t used_base = 528384;

  // largest H-phase width whose h buffer ((16384+128) rows x hp bf16) fits in ws
  int hp = 128;
  const int cands[6] = {4096, 2048, 1024, 512, 256, 128};
  for (int ci = 0; ci < 6; ++ci) {
    if (used_base + (size_t)16512 * cands[ci] * 2 <= ws_size) { hp = cands[ci]; break; }
  }

  hipMemsetAsync(counts, 0, 64, stream);
  hipMemsetAsync(out, 0, (size_t)NTOK * DDIM * 4, stream);
  gate_kernel<<<NTOK / 4, 256, 0, stream>>>(x, Wg, bg, counts, pair_tok, pair_w);
  offsets_kernel<<<1, 64, 0, stream>>>(counts, offsets);
  for (int p0 = 0; p0 < HDIM; p0 += hp) {
    gemm1_kernel<<<dim3(hp / 128, 64, NEXP), 256, 0, stream>>>(
        x, W1, b1, counts, offsets, pair_tok, hbuf, hp, p0);
    gemm2_kernel<<<dim3(DDIM / 128, 64, NEXP), 256, 0, stream>>>(
        hbuf, W2, b2, counts, offsets, pair_tok, pair_w, out, hp, p0, p0 == 0 ? 1 : 0);
  }
}

// Round 3
// 1016.357 us; speedup vs baseline: 1.1229x; 1.1229x over previous
//
#include <hip/hip_runtime.h>

typedef unsigned short u16;
typedef __attribute__((ext_vector_type(8))) short bf16x8;
typedef __attribute__((ext_vector_type(8))) unsigned short u16x8;
typedef __attribute__((ext_vector_type(4))) float f32x4;

#define NTOK 8192
#define DDIM 1024
#define HDIM 4096
#define NEXP 8

typedef __attribute__((address_space(1))) const void gvoid;
typedef __attribute__((address_space(3))) void lvoid;

__device__ __forceinline__ u16 f2b(float f) {
  unsigned u = __float_as_uint(f);
  u += 0x7fffu + ((u >> 16) & 1u);   // RNE
  return (u16)(u >> 16);
}
__device__ __forceinline__ void glds16(const void* g, void* l) {
  __builtin_amdgcn_global_load_lds((gvoid*)g, (lvoid*)l, 16, 0, 0);
}

// ---------------- pre-pass: x fp32 -> bf16 ----------------------------------
__global__ void convert_x_kernel(const float* __restrict__ src, u16* __restrict__ dst) {
  size_t i = ((size_t)blockIdx.x * 256 + threadIdx.x) * 8;
  float4 a = *(const float4*)(src + i);
  float4 b = *(const float4*)(src + i + 4);
  u16x8 o;
  o[0] = f2b(a.x); o[1] = f2b(a.y); o[2] = f2b(a.z); o[3] = f2b(a.w);
  o[4] = f2b(b.x); o[5] = f2b(b.y); o[6] = f2b(b.z); o[7] = f2b(b.w);
  *(u16x8*)(dst + i) = o;
}

// ---------------- pre-pass: [R][C] fp32 -> [C][R] bf16 (per expert) ---------
__global__ void transpose_kernel(const float* __restrict__ src, u16* __restrict__ dst,
                                 int R, int C) {
  int e = blockIdx.z;
  src += (size_t)e * R * C;
  dst += (size_t)e * R * C;
  int r0 = blockIdx.y * 64, c0 = blockIdx.x * 64;
  __shared__ u16 T[64][68];   // row stride 136 B: 8B-aligned, 2-way bank alias (free)
  int t = threadIdx.x;
  int rr = t >> 4, cc = (t & 15) * 4;
#pragma unroll
  for (int i = 0; i < 4; ++i) {
    int r = i * 16 + rr;
    float4 v = *(const float4*)(src + (size_t)(r0 + r) * C + c0 + cc);
    T[cc + 0][r] = f2b(v.x);
    T[cc + 1][r] = f2b(v.y);
    T[cc + 2][r] = f2b(v.z);
    T[cc + 3][r] = f2b(v.w);
  }
  __syncthreads();
#pragma unroll
  for (int i = 0; i < 4; ++i) {
    int c = i * 16 + rr;
    ushort4 o = *(const ushort4*)&T[c][cc];
    *(ushort4*)(dst + (size_t)(c0 + c) * R + r0 + cc) = o;
  }
}

// ---------------- gating: softmax over 8 experts, top-2, bucket by expert ----
__global__ void gate_kernel(const float* __restrict__ x, const float* __restrict__ Wg,
                            const float* __restrict__ bg, int* __restrict__ counts,
                            int* __restrict__ pair_tok, float* __restrict__ pair_w)
{
  int lane = threadIdx.x & 63;
  int wave = threadIdx.x >> 6;
  int tok = blockIdx.x * 4 + wave;
  const float* xr = x + (size_t)tok * DDIM + lane * 16;
  float acc[NEXP];
#pragma unroll
  for (int e = 0; e < NEXP; ++e) acc[e] = 0.f;
#pragma unroll
  for (int j = 0; j < 16; ++j) {
    float xf = xr[j];
    const float* wr = Wg + (size_t)(lane * 16 + j) * NEXP;
    float4 wa = *(const float4*)(wr);
    float4 wb = *(const float4*)(wr + 4);
    acc[0] = fmaf(xf, wa.x, acc[0]);
    acc[1] = fmaf(xf, wa.y, acc[1]);
    acc[2] = fmaf(xf, wa.z, acc[2]);
    acc[3] = fmaf(xf, wa.w, acc[3]);
    acc[4] = fmaf(xf, wb.x, acc[4]);
    acc[5] = fmaf(xf, wb.y, acc[5]);
    acc[6] = fmaf(xf, wb.z, acc[6]);
    acc[7] = fmaf(xf, wb.w, acc[7]);
  }
#pragma unroll
  for (int off = 32; off > 0; off >>= 1) {
#pragma unroll
    for (int e = 0; e < NEXP; ++e) acc[e] += __shfl_xor(acc[e], off, 64);
  }
  if (lane == 0) {
    float l[NEXP];
    float mx = -3.4e38f;
#pragma unroll
    for (int e = 0; e < NEXP; ++e) { l[e] = acc[e] + bg[e]; mx = fmaxf(mx, l[e]); }
    float s = 0.f;
#pragma unroll
    for (int e = 0; e < NEXP; ++e) { l[e] = __expf(l[e] - mx); s += l[e]; }
    float inv = 1.f / s;
    float v1 = -1.f; int i1 = 0;
#pragma unroll
    for (int e = 0; e < NEXP; ++e) { if (l[e] > v1) { v1 = l[e]; i1 = e; } }
    float v2 = -1.f; int i2 = 0;
#pragma unroll
    for (int e = 0; e < NEXP; ++e) { if (e != i1 && l[e] > v2) { v2 = l[e]; i2 = e; } }
    int p1 = atomicAdd(&counts[i1], 1);
    pair_tok[i1 * NTOK + p1] = tok;
    pair_w[i1 * NTOK + p1] = v1 * inv;   // raw top-k softmax prob (not renormalized)
    int p2 = atomicAdd(&counts[i2], 1);
    pair_tok[i2 * NTOK + p2] = tok;
    pair_w[i2 * NTOK + p2] = v2 * inv;
  }
}

__global__ void offsets_kernel(const int* __restrict__ counts, int* __restrict__ offsets) {
  if (threadIdx.x == 0) {
    int s = 0;
    for (int e = 0; e < NEXP; ++e) { offsets[e] = s; s += counts[e]; }
  }
}

// ---------------- grouped GEMM1: h = relu(gather(xb) @ W1T[e]^T + b1[e]) ----
// xb: [NTOK][D] bf16; W1T: [E][H][D] bf16 (K-contiguous rows)
__global__ __launch_bounds__(256) void gemm1_kernel(
    const u16* __restrict__ xb, const u16* __restrict__ W1T,
    const float* __restrict__ b1, const int* __restrict__ counts,
    const int* __restrict__ offsets, const int* __restrict__ pair_tok,
    u16* __restrict__ h, int hp, int p0)
{
  int e = blockIdx.z;
  int cnt = counts[e];
  int i0 = blockIdx.y * 128;
  if (i0 >= cnt) return;
  int n0 = blockIdx.x * 128;               // column offset within this phase

  __shared__ __align__(16) u16 As[128 * 32];
  __shared__ __align__(16) u16 Bs[128 * 32];

  int t = threadIdx.x;
  int lane = t & 63;
  int wave = t >> 6;
  int rlim = cnt - i0;

  const int* tokp = pair_tok + e * NTOK + i0;
  int arow = t >> 2;
  int c8 = (t & 3) * 8;
  const u16* xa0 = xb + (size_t)tokp[min(arow, rlim - 1)] * DDIM + c8;
  const u16* xa1 = xb + (size_t)tokp[min(arow + 64, rlim - 1)] * DDIM + c8;
  const u16* wb0 = W1T + (size_t)e * HDIM * DDIM + (size_t)(p0 + n0 + arow) * DDIM + c8;
  const u16* wb1 = wb0 + (size_t)64 * DDIM;
  u16* As0 = As + wave * 512;  u16* As1 = As + 2048 + wave * 512;
  u16* Bs0 = Bs + wave * 512;  u16* Bs1 = Bs + 2048 + wave * 512;

  f32x4 acc[4][4] = {};
  int wrr = (wave >> 1) * 64;
  int wc = (wave & 1) * 64;
  int ln = lane & 15;
  int q = lane >> 4;

  for (int k0 = 0; k0 < DDIM; k0 += 32) {
    __syncthreads();
    glds16(xa0 + k0, As0);
    glds16(xa1 + k0, As1);
    glds16(wb0 + k0, Bs0);
    glds16(wb1 + k0, Bs1);
    __syncthreads();
    bf16x8 af[4], bfr[4];
#pragma unroll
    for (int mt = 0; mt < 4; ++mt)
      af[mt] = *(const bf16x8*)(As + (wrr + mt * 16 + ln) * 32 + q * 8);
#pragma unroll
    for (int nt = 0; nt < 4; ++nt)
      bfr[nt] = *(const bf16x8*)(Bs + (wc + nt * 16 + ln) * 32 + q * 8);
#pragma unroll
    for (int mt = 0; mt < 4; ++mt)
#pragma unroll
      for (int nt = 0; nt < 4; ++nt)
        acc[mt][nt] = __builtin_amdgcn_mfma_f32_16x16x32_bf16(af[mt], bfr[nt], acc[mt][nt], 0, 0, 0);
  }

  int ob = offsets[e];
  float bb[4];
#pragma unroll
  for (int nt = 0; nt < 4; ++nt)
    bb[nt] = b1[(size_t)e * HDIM + p0 + n0 + wc + nt * 16 + ln];
  size_t hbase = (size_t)(ob + i0) * hp + n0 + wc;
#pragma unroll
  for (int mt = 0; mt < 4; ++mt) {
#pragma unroll
    for (int r = 0; r < 4; ++r) {
      int row = wrr + mt * 16 + q * 4 + r;
      if (row < rlim) {
        u16* hrow = h + hbase + (size_t)row * hp;
#pragma unroll
        for (int nt = 0; nt < 4; ++nt) {
          float v = acc[mt][nt][r] + bb[nt];
          hrow[nt * 16 + ln] = f2b(fmaxf(v, 0.f));
        }
      }
    }
  }
}

// ---------------- grouped GEMM2: out += w * (h @ W2T[e]^T + b2[e]) -----------
// h: [rows][hp] bf16; W2T: [E][D][H] bf16 (K-contiguous rows)
__global__ __launch_bounds__(256) void gemm2_kernel(
    const u16* __restrict__ h, const u16* __restrict__ W2T,
    const float* __restrict__ b2v, const int* __restrict__ counts,
    const int* __restrict__ offsets, const int* __restrict__ pair_tok,
    const float* __restrict__ pair_w, float* __restrict__ out,
    int hp, int p0, int addb2)
{
  int e = blockIdx.z;
  int cnt = counts[e];
  int i0 = blockIdx.y * 128;
  if (i0 >= cnt) return;
  int n0 = blockIdx.x * 128;

  __shared__ __align__(16) u16 As[128 * 32];
  __shared__ __align__(16) u16 Bs[128 * 32];

  int t = threadIdx.x;
  int lane = t & 63;
  int wave = t >> 6;
  int rlim = cnt - i0;
  int rbase = offsets[e] + i0;

  int arow = t >> 2;
  int c8 = (t & 3) * 8;
  const u16* ha0 = h + (size_t)(rbase + arow) * hp + c8;
  const u16* ha1 = h + (size_t)(rbase + arow + 64) * hp + c8;
  const u16* wb0 = W2T + (size_t)e * DDIM * HDIM + (size_t)(n0 + arow) * HDIM + p0 + c8;
  const u16* wb1 = wb0 + (size_t)64 * HDIM;
  u16* As0 = As + wave * 512;  u16* As1 = As + 2048 + wave * 512;
  u16* Bs0 = Bs + wave * 512;  u16* Bs1 = Bs + 2048 + wave * 512;

  f32x4 acc[4][4] = {};
  int wrr = (wave >> 1) * 64;
  int wc = (wave & 1) * 64;
  int ln = lane & 15;
  int q = lane >> 4;

  for (int k0 = 0; k0 < hp; k0 += 32) {
    __syncthreads();
    glds16(ha0 + k0, As0);
    glds16(ha1 + k0, As1);
    glds16(wb0 + k0, Bs0);
    glds16(wb1 + k0, Bs1);
    __syncthreads();
    bf16x8 af[4], bfr[4];
#pragma unroll
    for (int mt = 0; mt < 4; ++mt)
      af[mt] = *(const bf16x8*)(As + (wrr + mt * 16 + ln) * 32 + q * 8);
#pragma unroll
    for (int nt = 0; nt < 4; ++nt)
      bfr[nt] = *(const bf16x8*)(Bs + (wc + nt * 16 + ln) * 32 + q * 8);
#pragma unroll
    for (int mt = 0; mt < 4; ++mt)
#pragma unroll
      for (int nt = 0; nt < 4; ++nt)
        acc[mt][nt] = __builtin_amdgcn_mfma_f32_16x16x32_bf16(af[mt], bfr[nt], acc[mt][nt], 0, 0, 0);
  }

  float bb[4];
#pragma unroll
  for (int nt = 0; nt < 4; ++nt)
    bb[nt] = addb2 ? b2v[(size_t)e * DDIM + n0 + wc + nt * 16 + ln] : 0.f;
#pragma unroll
  for (int mt = 0; mt < 4; ++mt) {
#pragma unroll
    for (int r = 0; r < 4; ++r) {
      int row = wrr + mt * 16 + q * 4 + r;
      if (row < rlim) {
        int i = i0 + row;
        int tk = pair_tok[e * NTOK + i];
        float w = pair_w[e * NTOK + i];
        float* orow = out + (size_t)tk * DDIM + n0 + wc;
#pragma unroll
        for (int nt = 0; nt < 4; ++nt)
          atomicAdd(orow + nt * 16 + ln, (acc[mt][nt][r] + bb[nt]) * w);
      }
    }
  }
}

// ---------------- host launch ------------------------------------------------
extern "C" void kernel_launch(void* const* d_in, const int* in_sizes, int n_in,
                              void* d_out, int out_size, void* d_ws, size_t ws_size,
                              hipStream_t stream)
{
  const float* x  = (const float*)d_in[0];
  const float* Wg = (const float*)d_in[1];
  const float* bg = (const float*)d_in[2];
  const float* W1 = (const float*)d_in[3];
  const float* b1 = (const float*)d_in[4];
  const float* W2 = (const float*)d_in[5];
  const float* b2 = (const float*)d_in[6];
  float* out = (float*)d_out;

  char* ws = (char*)d_ws;
  int*   counts   = (int*)(ws + 0);
  int*   offsets  = (int*)(ws + 64);
  int*   pair_tok = (int*)(ws + 4096);
  float* pair_w   = (float*)(ws + 4096 + 262144);
  u16*   xb       = (u16*)(ws + 528384);                       // 16.78 MB
  u16*   W1T      = (u16*)(ws + 528384 + 16777216);            // 67.1 MB
  u16*   W2T      = (u16*)(ws + 528384 + 16777216 + 67108864); // 67.1 MB
  u16*   hbuf     = (u16*)(ws + 528384 + 16777216 + 2 * (size_t)67108864);
  size_t used_base = 528384 + 16777216 + 2 * (size_t)67108864;

  // largest H-phase width whose h buffer ((16384+128) rows x hp bf16) fits in ws
  int hp = 128;
  const int cands[6] = {4096, 2048, 1024, 512, 256, 128};
  for (int ci = 0; ci < 6; ++ci) {
    if (used_base + (size_t)16512 * cands[ci] * 2 <= ws_size) { hp = cands[ci]; break; }
  }

  hipMemsetAsync(counts, 0, 64, stream);
  hipMemsetAsync(out, 0, (size_t)NTOK * DDIM * 4, stream);
  convert_x_kernel<<<NTOK * DDIM / 2048, 256, 0, stream>>>(x, xb);
  // W1 [E][D][H] -> W1T [E][H][D]
  transpose_kernel<<<dim3(HDIM / 64, DDIM / 64, NEXP), 256, 0, stream>>>(W1, W1T, DDIM, HDIM);
  // W2 [E][H][D] -> W2T [E][D][H]
  transpose_kernel<<<dim3(DDIM / 64, HDIM / 64, NEXP), 256, 0, stream>>>(W2, W2T, HDIM, DDIM);
  gate_kernel<<<NTOK / 4, 256, 0, stream>>>(x, Wg, bg, counts, pair_tok, pair_w);
  offsets_kernel<<<1, 64, 0, stream>>>(counts, offsets);
  for (int p0 = 0; p0 < HDIM; p0 += hp) {
    gemm1_kernel<<<dim3(hp / 128, 64, NEXP), 256, 0, stream>>>(
        xb, W1T, b1, counts, offsets, pair_tok, hbuf, hp, p0);
    gemm2_kernel<<<dim3(DDIM / 128, 64, NEXP), 256, 0, stream>>>(
        hbuf, W2T, b2, counts, offsets, pair_tok, pair_w, out, hp, p0, p0 == 0 ? 1 : 0);
  }
}